// Round 1
// baseline (2217.684 us; speedup 1.0000x reference)
//
#include <hip/hip_runtime.h>
#include <hip/hip_fp16.h>
#include <stdint.h>

#define VV 32000
#define HH 256
#define BB 32
#define TT 128
#define VH 32256  // V + H

typedef _Float16 f16;
typedef _Float16 f16x2 __attribute__((ext_vector_type(2)));
typedef _Float16 f16x8 __attribute__((ext_vector_type(8)));
typedef float f32x4 __attribute__((ext_vector_type(4)));

static __device__ __forceinline__ float dot2f(uint32_t w, uint32_t h, float acc){
  f16x2 a = __builtin_bit_cast(f16x2, w);
  f16x2 b = __builtin_bit_cast(f16x2, h);
  acc = fmaf((float)a[0], (float)b[0], acc);   // v_fma_mix candidates
  acc = fmaf((float)a[1], (float)b[1], acc);
  return acc;
}

// ---------------- gather: g[t*32+b][o] = W_gate[row][tok] + bias (o: 0..255 z, 256..511 r, 512..767 h)
__global__ void k_gather(const int* __restrict__ X,
                         const float* __restrict__ Wz, const float* __restrict__ bz,
                         const float* __restrict__ Wr, const float* __restrict__ br,
                         const float* __restrict__ Wh, const float* __restrict__ bh,
                         float* __restrict__ g_buf){
  int tb = blockIdx.x;              // t*32 + b
  int t = tb >> 5, b = tb & 31;
  int tok = X[b*TT + t];
  int o = threadIdx.x;              // 0..255
  g_buf[(size_t)tb*768 + o]       = Wz[(size_t)o*VH + tok] + bz[o];
  g_buf[(size_t)tb*768 + 256 + o] = Wr[(size_t)o*VH + tok] + br[o];
  g_buf[(size_t)tb*768 + 512 + o] = Wh[(size_t)o*VH + tok] + bh[o];
}

// ---------------- pack recurrent weights into per-thread register layout (f16 pairs)
// thread t512: ko = t512&7 (K-chunk k in [ko*32, ko*32+32)), no = t512>>3
// outputs: ol<8 -> o = no*8+ol (o<256: Wz row o; else Wr row o-256); ol in [8,12): Wh row no*4+(ol-8)
__global__ void k_pack(const float* __restrict__ Wz, const float* __restrict__ Wr,
                       const float* __restrict__ Wh, uint32_t* __restrict__ Wpack){
  int idx = blockIdx.x*256 + threadIdx.x;
  if (idx >= 512*192) return;
  int t512 = idx / 192, rem = idx - t512*192;
  int ol = rem >> 4, p = rem & 15;
  int ko = t512 & 7, no = t512 >> 3;
  int k = ko*32 + p*2;
  const float* W; int row;
  if (ol < 8){ int o = no*8 + ol; if (o < 256){ W = Wz; row = o; } else { W = Wr; row = o - 256; } }
  else { W = Wh; row = no*4 + (ol - 8); }
  float a = W[(size_t)row*VH + VV + k];
  float c = W[(size_t)row*VH + VV + k + 1];
  f16x2 v; v[0] = (f16)a; v[1] = (f16)c;
  Wpack[idx] = __builtin_bit_cast(uint32_t, v);
}

// ---------------- recurrence: 32 blocks (one batch chain each), 512 threads, weights in registers
__global__ __launch_bounds__(512) void k_recur(const float* __restrict__ H0,
                                               const uint32_t* __restrict__ Wpack,
                                               const float* __restrict__ g_buf,
                                               f16* __restrict__ Hn16,
                                               float* __restrict__ hf_out){
  __shared__ __align__(16) uint32_t hs16[128];   // Hs as f16 pairs
  __shared__ float hs32[256];                    // Hs in f32 (state of record)
  __shared__ float z_s[256];
  __shared__ __align__(16) uint32_t rHs[128];    // r*Hs as f16 pairs
  __shared__ float g_s[2][768];                  // double-buffered gathered gate inputs

  const int b = blockIdx.x;
  const int tid = threadIdx.x;
  const int ko = tid & 7, no = tid >> 3;

  // load 192 packed weight dwords into registers (fully unrolled, static indices)
  uint32_t w[12][16];
  {
    const uint4* src = (const uint4*)(Wpack + (size_t)tid*192);
    #pragma unroll
    for (int j=0;j<48;j++){
      uint4 v = src[j];
      int f = j*4;
      w[(f+0)>>4][(f+0)&15] = v.x;
      w[(f+1)>>4][(f+1)&15] = v.y;
      w[(f+2)>>4][(f+2)&15] = v.z;
      w[(f+3)>>4][(f+3)&15] = v.w;
    }
  }

  if (tid < 256) hs32[tid] = H0[b*HH + tid];
  {
    g_s[0][tid] = g_buf[(size_t)b*768 + tid];
    if (tid < 256) g_s[0][512 + tid] = g_buf[(size_t)b*768 + 512 + tid];
  }
  __syncthreads();
  if (tid < 128){
    f16x2 v; v[0] = (f16)hs32[2*tid]; v[1] = (f16)hs32[2*tid+1];
    hs16[tid] = __builtin_bit_cast(uint32_t, v);
  }
  __syncthreads();

  for (int t = 0; t < TT; t++){
    const int cur = t & 1, nxt = cur ^ 1;
    float gn0 = 0.f, gn1 = 0.f;
    if (t < TT-1){
      const float* gr = g_buf + (size_t)((t+1)*BB + b)*768;
      gn0 = gr[tid];
      if (tid < 256) gn1 = gr[512 + tid];
    }

    // ---- phase 1: z and r pre-activations (o in [0,512))
    uint32_t hp[16];
    {
      const uint2* hsp = (const uint2*)hs16;
      #pragma unroll
      for (int j=0;j<8;j++){ uint2 v = hsp[ko*8 + j]; hp[2*j] = v.x; hp[2*j+1] = v.y; }
    }
    float acc[8];
    #pragma unroll
    for (int ol=0;ol<8;ol++) acc[ol] = 0.f;
    #pragma unroll
    for (int p=0;p<16;p++)
      #pragma unroll
      for (int ol=0;ol<8;ol++)
        acc[ol] = dot2f(w[ol][p], hp[p], acc[ol]);
    #pragma unroll
    for (int ol=0;ol<8;ol++){
      float v2 = acc[ol];
      v2 += __shfl_xor(v2, 1);
      v2 += __shfl_xor(v2, 2);
      v2 += __shfl_xor(v2, 4);
      acc[ol] = v2;
    }
    if (ko == 0){
      float sv[8];
      #pragma unroll
      for (int ol=0;ol<8;ol++){
        float pre = acc[ol] + g_s[cur][no*8 + ol];
        sv[ol] = 1.f / (1.f + __expf(-pre));
      }
      if (no < 32){
        #pragma unroll
        for (int ol=0;ol<8;ol++) z_s[no*8 + ol] = sv[ol];
      } else {
        const int h0 = (no - 32)*8;
        #pragma unroll
        for (int q=0;q<4;q++){
          float r0 = sv[2*q]   * hs32[h0 + 2*q];
          float r1 = sv[2*q+1] * hs32[h0 + 2*q+1];
          f16x2 v; v[0] = (f16)r0; v[1] = (f16)r1;
          rHs[h0/2 + q] = __builtin_bit_cast(uint32_t, v);
        }
      }
    }
    __syncthreads();

    // ---- phase 2: h~ = tanh(gh + (r*Hs)@Wh^T), Hn = z*h~ + (1-z)*Hs
    uint32_t rp[16];
    {
      const uint2* rpp = (const uint2*)rHs;
      #pragma unroll
      for (int j=0;j<8;j++){ uint2 v = rpp[ko*8 + j]; rp[2*j] = v.x; rp[2*j+1] = v.y; }
    }
    float a2[4];
    #pragma unroll
    for (int oi=0;oi<4;oi++) a2[oi] = 0.f;
    #pragma unroll
    for (int p=0;p<16;p++)
      #pragma unroll
      for (int oi=0;oi<4;oi++)
        a2[oi] = dot2f(w[8+oi][p], rp[p], a2[oi]);
    #pragma unroll
    for (int oi=0;oi<4;oi++){
      float v2 = a2[oi];
      v2 += __shfl_xor(v2, 1);
      v2 += __shfl_xor(v2, 2);
      v2 += __shfl_xor(v2, 4);
      a2[oi] = v2;
    }
    if (ko == 0){
      const int h0 = no*4;
      float hn[4];
      #pragma unroll
      for (int oi=0;oi<4;oi++){
        float pre = a2[oi] + g_s[cur][512 + h0 + oi];
        float ax = fabsf(pre);
        float e = __expf(2.f*ax);
        float th = 1.f - 2.f/(e + 1.f);      // tanh(|x|), safe at inf
        th = copysignf(th, pre);
        float z = z_s[h0 + oi];
        hn[oi] = z*th + (1.f - z)*hs32[h0 + oi];
      }
      #pragma unroll
      for (int oi=0;oi<4;oi++) hs32[h0 + oi] = hn[oi];
      f16x2 v0; v0[0] = (f16)hn[0]; v0[1] = (f16)hn[1];
      f16x2 v1; v1[0] = (f16)hn[2]; v1[1] = (f16)hn[3];
      uint32_t u0 = __builtin_bit_cast(uint32_t, v0);
      uint32_t u1 = __builtin_bit_cast(uint32_t, v1);
      hs16[no*2]   = u0;
      hs16[no*2+1] = u1;
      uint2* dst = (uint2*)(Hn16 + (size_t)(t*BB + b)*HH + h0);
      *dst = make_uint2(u0, u1);
      if (t == TT-1){
        #pragma unroll
        for (int oi=0;oi<4;oi++) hf_out[b*HH + h0 + oi] = hn[oi];
      }
    }
    if (t < TT-1){
      g_s[nxt][tid] = gn0;
      if (tid < 256) g_s[nxt][512 + tid] = gn1;
    }
    __syncthreads();
  }
}

// ---------------- output GEMM: Y[4096][32000] = Hn16[4096][256] @ Wo^T (f16 MFMA) + bo
__global__ __launch_bounds__(256) void k_gemm(const f16* __restrict__ A, const float* __restrict__ Wo,
                                              const float* __restrict__ bo, float* __restrict__ Y){
  __shared__ __align__(16) f16 a_lds[128*128];
  __shared__ __align__(16) f16 b_lds[128*128];
  const int n0 = blockIdx.x * 128;
  const int m0 = blockIdx.y * 128;
  const int tid = threadIdx.x;
  const int lane = tid & 63, wave = tid >> 6;
  const int wm = wave >> 1, wn = wave & 1;

  f32x4 acc[4][4];
  {
    f32x4 z = {0.f, 0.f, 0.f, 0.f};
    #pragma unroll
    for (int i=0;i<4;i++)
      #pragma unroll
      for (int j=0;j<4;j++) acc[i][j] = z;
  }

  const int srow = tid >> 1, seg = tid & 1;
  #pragma unroll 1
  for (int kt=0; kt<2; kt++){
    const int k0 = kt*128;
    // stage A (f16 direct) and B (f32 -> f16 convert), XOR-swizzled LDS
    {
      const uint4* asrc = (const uint4*)(A + (size_t)(m0+srow)*256 + k0 + seg*64);
      #pragma unroll
      for (int j=0;j<8;j++){
        uint4 v = asrc[j];
        int byte = (srow*256 + seg*128 + j*16) ^ ((srow&7)<<4);
        *(uint4*)((char*)a_lds + byte) = v;
      }
      const float4* bsrc = (const float4*)(Wo + (size_t)(n0+srow)*256 + k0 + seg*64);
      #pragma unroll
      for (int j=0;j<8;j++){
        float4 f0 = bsrc[2*j], f1 = bsrc[2*j+1];
        f16x8 hv;
        hv[0]=(f16)f0.x; hv[1]=(f16)f0.y; hv[2]=(f16)f0.z; hv[3]=(f16)f0.w;
        hv[4]=(f16)f1.x; hv[5]=(f16)f1.y; hv[6]=(f16)f1.z; hv[7]=(f16)f1.w;
        int byte = (srow*256 + seg*128 + j*16) ^ ((srow&7)<<4);
        *(f16x8*)((char*)b_lds + byte) = hv;
      }
    }
    __syncthreads();
    #pragma unroll
    for (int kk=0; kk<4; kk++){
      const int kbyte = kk*64 + (lane>>4)*16;
      f16x8 af[4], bf[4];
      #pragma unroll
      for (int mi=0;mi<4;mi++){
        int row = wm*64 + mi*16 + (lane&15);
        int byte = (row*256 + kbyte) ^ ((row&7)<<4);
        af[mi] = *(const f16x8*)((const char*)a_lds + byte);
      }
      #pragma unroll
      for (int nj=0;nj<4;nj++){
        int nl = wn*64 + nj*16 + (lane&15);
        int byte = (nl*256 + kbyte) ^ ((nl&7)<<4);
        bf[nj] = *(const f16x8*)((const char*)b_lds + byte);
      }
      #pragma unroll
      for (int mi=0;mi<4;mi++)
        #pragma unroll
        for (int nj=0;nj<4;nj++)
          acc[mi][nj] = __builtin_amdgcn_mfma_f32_16x16x32_f16(af[mi], bf[nj], acc[mi][nj], 0, 0, 0);
    }
    __syncthreads();
  }
  // epilogue: C/D map: col = lane&15, row = (lane>>4)*4 + reg
  #pragma unroll
  for (int nj=0;nj<4;nj++){
    const int col = n0 + wn*64 + nj*16 + (lane & 15);
    const float bov = bo[col];
    #pragma unroll
    for (int mi=0;mi<4;mi++){
      const int rbase = m0 + wm*64 + mi*16 + (lane>>4)*4;
      #pragma unroll
      for (int r=0;r<4;r++){
        Y[(size_t)(rbase + r)*VV + col] = acc[mi][nj][r] + bov;
      }
    }
  }
}

extern "C" void kernel_launch(void* const* d_in, const int* in_sizes, int n_in,
                              void* d_out, int out_size, void* d_ws, size_t ws_size,
                              hipStream_t stream){
  const int*   X  = (const int*)d_in[0];
  const float* H0 = (const float*)d_in[1];
  const float* Wz = (const float*)d_in[2];
  const float* bz = (const float*)d_in[3];
  const float* Wr = (const float*)d_in[4];
  const float* br = (const float*)d_in[5];
  const float* Wh = (const float*)d_in[6];
  const float* bh = (const float*)d_in[7];
  const float* Wo = (const float*)d_in[8];
  const float* bo = (const float*)d_in[9];
  float* out = (float*)d_out;

  char* ws = (char*)d_ws;
  float*    g_buf = (float*)ws;                               // 4096*768*4  = 12,582,912 B
  uint32_t* Wpack = (uint32_t*)(ws + 12582912);               // 512*192*4   =    393,216 B
  f16*      Hn16  = (f16*)(ws + 12582912 + 393216);           // 4096*256*2  =  2,097,152 B

  k_gather<<<4096, 256, 0, stream>>>(X, Wz, bz, Wr, br, Wh, bh, g_buf);
  k_pack<<<384, 256, 0, stream>>>(Wz, Wr, Wh, Wpack);
  k_recur<<<32, 512, 0, stream>>>(H0, Wpack, g_buf, Hn16, out + 131072000LL);
  k_gemm<<<dim3(250, 32), 256, 0, stream>>>(Hn16, Wo, bo, out);
}

// Round 2
// 752.296 us; speedup vs baseline: 2.9479x; 2.9479x over previous
//
#include <hip/hip_runtime.h>
#include <hip/hip_fp16.h>
#include <stdint.h>

#define VV 32000
#define HH 256
#define BB 32
#define TT 128
#define VH 32256  // V + H

typedef _Float16 f16;
typedef _Float16 f16x2 __attribute__((ext_vector_type(2)));
typedef _Float16 f16x8 __attribute__((ext_vector_type(8)));
typedef float f32x4 __attribute__((ext_vector_type(4)));

// v_dot2_f32_f16: 2 f16 MACs with f32 accumulate in one instruction
static __device__ __forceinline__ float dot2f(uint32_t w, uint32_t h, float acc){
  f16x2 a = __builtin_bit_cast(f16x2, w);
  f16x2 b = __builtin_bit_cast(f16x2, h);
#if __has_builtin(__builtin_amdgcn_fdot2)
  return __builtin_amdgcn_fdot2(a, b, acc, false);
#else
  acc = fmaf((float)a[0], (float)b[0], acc);
  acc = fmaf((float)a[1], (float)b[1], acc);
  return acc;
#endif
}

// ---------------- gather: g[t*32+b][o] = W_gate[row][tok] + bias (o: 0..255 z, 256..511 r, 512..767 h)
__global__ void k_gather(const int* __restrict__ X,
                         const float* __restrict__ Wz, const float* __restrict__ bz,
                         const float* __restrict__ Wr, const float* __restrict__ br,
                         const float* __restrict__ Wh, const float* __restrict__ bh,
                         float* __restrict__ g_buf){
  int tb = blockIdx.x;              // t*32 + b
  int t = tb >> 5, b = tb & 31;
  int tok = X[b*TT + t];
  int o = threadIdx.x;              // 0..255
  g_buf[(size_t)tb*768 + o]       = Wz[(size_t)o*VH + tok] + bz[o];
  g_buf[(size_t)tb*768 + 256 + o] = Wr[(size_t)o*VH + tok] + br[o];
  g_buf[(size_t)tb*768 + 512 + o] = Wh[(size_t)o*VH + tok] + bh[o];
}

// ---------------- pack recurrent weights into per-thread register layout (f16 pairs)
__global__ void k_pack(const float* __restrict__ Wz, const float* __restrict__ Wr,
                       const float* __restrict__ Wh, uint32_t* __restrict__ Wpack){
  int idx = blockIdx.x*256 + threadIdx.x;
  if (idx >= 512*192) return;
  int t512 = idx / 192, rem = idx - t512*192;
  int ol = rem >> 4, p = rem & 15;
  int ko = t512 & 7, no = t512 >> 3;
  int k = ko*32 + p*2;
  const float* W; int row;
  if (ol < 8){ int o = no*8 + ol; if (o < 256){ W = Wz; row = o; } else { W = Wr; row = o - 256; } }
  else { W = Wh; row = no*4 + (ol - 8); }
  float a = W[(size_t)row*VH + VV + k];
  float c = W[(size_t)row*VH + VV + k + 1];
  f16x2 v; v[0] = (f16)a; v[1] = (f16)c;
  Wpack[idx] = __builtin_bit_cast(uint32_t, v);
}

// ---------------- recurrence: 32 blocks (one batch chain each), 512 threads, weights in registers
// __launch_bounds__(512, 2): 2 waves/EU floor -> 256-VGPR cap -> no spill of w[12][16]
__global__ __launch_bounds__(512, 2) void k_recur(const float* __restrict__ H0,
                                               const uint32_t* __restrict__ Wpack,
                                               const float* __restrict__ g_buf,
                                               f16* __restrict__ Hn16,
                                               float* __restrict__ hf_out){
  __shared__ __align__(16) uint32_t hs16[128];   // Hs as f16 pairs
  __shared__ float hs32[256];                    // Hs in f32 (state of record)
  __shared__ float z_s[256];
  __shared__ __align__(16) uint32_t rHs[128];    // r*Hs as f16 pairs
  __shared__ float g_s[2][768];                  // double-buffered gathered gate inputs

  const int b = blockIdx.x;
  const int tid = threadIdx.x;
  const int ko = tid & 7, no = tid >> 3;

  // load 192 packed weight dwords into registers (fully unrolled, static indices)
  uint32_t w[12][16];
  {
    const uint4* src = (const uint4*)(Wpack + (size_t)tid*192);
    #pragma unroll
    for (int j=0;j<48;j++){
      uint4 v = src[j];
      int f = j*4;
      w[(f+0)>>4][(f+0)&15] = v.x;
      w[(f+1)>>4][(f+1)&15] = v.y;
      w[(f+2)>>4][(f+2)&15] = v.z;
      w[(f+3)>>4][(f+3)&15] = v.w;
    }
  }

  if (tid < 256) hs32[tid] = H0[b*HH + tid];
  {
    g_s[0][tid] = g_buf[(size_t)b*768 + tid];
    if (tid < 256) g_s[0][512 + tid] = g_buf[(size_t)b*768 + 512 + tid];
  }
  __syncthreads();
  if (tid < 128){
    f16x2 v; v[0] = (f16)hs32[2*tid]; v[1] = (f16)hs32[2*tid+1];
    hs16[tid] = __builtin_bit_cast(uint32_t, v);
  }
  __syncthreads();

  for (int t = 0; t < TT; t++){
    const int cur = t & 1, nxt = cur ^ 1;
    float gn0 = 0.f, gn1 = 0.f;
    if (t < TT-1){
      const float* gr = g_buf + (size_t)((t+1)*BB + b)*768;
      gn0 = gr[tid];
      if (tid < 256) gn1 = gr[512 + tid];
    }

    // ---- phase 1: z and r pre-activations (o in [0,512))
    uint32_t hp[16];
    {
      const uint2* hsp = (const uint2*)hs16;
      #pragma unroll
      for (int j=0;j<8;j++){ uint2 v = hsp[ko*8 + j]; hp[2*j] = v.x; hp[2*j+1] = v.y; }
    }
    float acc[8];
    #pragma unroll
    for (int ol=0;ol<8;ol++) acc[ol] = 0.f;
    #pragma unroll
    for (int p=0;p<16;p++)
      #pragma unroll
      for (int ol=0;ol<8;ol++)
        acc[ol] = dot2f(w[ol][p], hp[p], acc[ol]);
    #pragma unroll
    for (int ol=0;ol<8;ol++){
      float v2 = acc[ol];
      v2 += __shfl_xor(v2, 1);
      v2 += __shfl_xor(v2, 2);
      v2 += __shfl_xor(v2, 4);
      acc[ol] = v2;
    }
    if (ko == 0){
      float sv[8];
      #pragma unroll
      for (int ol=0;ol<8;ol++){
        float pre = acc[ol] + g_s[cur][no*8 + ol];
        sv[ol] = 1.f / (1.f + __expf(-pre));
      }
      if (no < 32){
        #pragma unroll
        for (int ol=0;ol<8;ol++) z_s[no*8 + ol] = sv[ol];
      } else {
        const int h0 = (no - 32)*8;
        #pragma unroll
        for (int q=0;q<4;q++){
          float r0 = sv[2*q]   * hs32[h0 + 2*q];
          float r1 = sv[2*q+1] * hs32[h0 + 2*q+1];
          f16x2 v; v[0] = (f16)r0; v[1] = (f16)r1;
          rHs[h0/2 + q] = __builtin_bit_cast(uint32_t, v);
        }
      }
    }
    __syncthreads();

    // ---- phase 2: h~ = tanh(gh + (r*Hs)@Wh^T), Hn = z*h~ + (1-z)*Hs
    uint32_t rp[16];
    {
      const uint2* rpp = (const uint2*)rHs;
      #pragma unroll
      for (int j=0;j<8;j++){ uint2 v = rpp[ko*8 + j]; rp[2*j] = v.x; rp[2*j+1] = v.y; }
    }
    float a2[4];
    #pragma unroll
    for (int oi=0;oi<4;oi++) a2[oi] = 0.f;
    #pragma unroll
    for (int p=0;p<16;p++)
      #pragma unroll
      for (int oi=0;oi<4;oi++)
        a2[oi] = dot2f(w[8+oi][p], rp[p], a2[oi]);
    #pragma unroll
    for (int oi=0;oi<4;oi++){
      float v2 = a2[oi];
      v2 += __shfl_xor(v2, 1);
      v2 += __shfl_xor(v2, 2);
      v2 += __shfl_xor(v2, 4);
      a2[oi] = v2;
    }
    if (ko == 0){
      const int h0 = no*4;
      float hn[4];
      #pragma unroll
      for (int oi=0;oi<4;oi++){
        float pre = a2[oi] + g_s[cur][512 + h0 + oi];
        float ax = fabsf(pre);
        float e = __expf(2.f*ax);
        float th = 1.f - 2.f/(e + 1.f);      // tanh(|x|), safe at inf
        th = copysignf(th, pre);
        float z = z_s[h0 + oi];
        hn[oi] = z*th + (1.f - z)*hs32[h0 + oi];
      }
      #pragma unroll
      for (int oi=0;oi<4;oi++) hs32[h0 + oi] = hn[oi];
      f16x2 v0; v0[0] = (f16)hn[0]; v0[1] = (f16)hn[1];
      f16x2 v1; v1[0] = (f16)hn[2]; v1[1] = (f16)hn[3];
      uint32_t u0 = __builtin_bit_cast(uint32_t, v0);
      uint32_t u1 = __builtin_bit_cast(uint32_t, v1);
      hs16[no*2]   = u0;
      hs16[no*2+1] = u1;
      uint2* dst = (uint2*)(Hn16 + (size_t)(t*BB + b)*HH + h0);
      *dst = make_uint2(u0, u1);
      if (t == TT-1){
        #pragma unroll
        for (int oi=0;oi<4;oi++) hf_out[b*HH + h0 + oi] = hn[oi];
      }
    }
    if (t < TT-1){
      g_s[nxt][tid] = gn0;
      if (tid < 256) g_s[nxt][512 + tid] = gn1;
    }
    __syncthreads();
  }
}

// ---------------- output GEMM: Y[4096][32000] = Hn16[4096][256] @ Wo^T (f16 MFMA) + bo
__global__ __launch_bounds__(256) void k_gemm(const f16* __restrict__ A, const float* __restrict__ Wo,
                                              const float* __restrict__ bo, float* __restrict__ Y){
  __shared__ __align__(16) f16 a_lds[128*128];
  __shared__ __align__(16) f16 b_lds[128*128];
  const int n0 = blockIdx.x * 128;
  const int m0 = blockIdx.y * 128;
  const int tid = threadIdx.x;
  const int lane = tid & 63, wave = tid >> 6;
  const int wm = wave >> 1, wn = wave & 1;

  f32x4 acc[4][4];
  {
    f32x4 z = {0.f, 0.f, 0.f, 0.f};
    #pragma unroll
    for (int i=0;i<4;i++)
      #pragma unroll
      for (int j=0;j<4;j++) acc[i][j] = z;
  }

  const int srow = tid >> 1, seg = tid & 1;
  #pragma unroll 1
  for (int kt=0; kt<2; kt++){
    const int k0 = kt*128;
    {
      const uint4* asrc = (const uint4*)(A + (size_t)(m0+srow)*256 + k0 + seg*64);
      #pragma unroll
      for (int j=0;j<8;j++){
        uint4 v = asrc[j];
        int byte = (srow*256 + seg*128 + j*16) ^ ((srow&7)<<4);
        *(uint4*)((char*)a_lds + byte) = v;
      }
      const float4* bsrc = (const float4*)(Wo + (size_t)(n0+srow)*256 + k0 + seg*64);
      #pragma unroll
      for (int j=0;j<8;j++){
        float4 f0 = bsrc[2*j], f1 = bsrc[2*j+1];
        f16x8 hv;
        hv[0]=(f16)f0.x; hv[1]=(f16)f0.y; hv[2]=(f16)f0.z; hv[3]=(f16)f0.w;
        hv[4]=(f16)f1.x; hv[5]=(f16)f1.y; hv[6]=(f16)f1.z; hv[7]=(f16)f1.w;
        int byte = (srow*256 + seg*128 + j*16) ^ ((srow&7)<<4);
        *(f16x8*)((char*)b_lds + byte) = hv;
      }
    }
    __syncthreads();
    #pragma unroll
    for (int kk=0; kk<4; kk++){
      const int kbyte = kk*64 + (lane>>4)*16;
      f16x8 af[4], bf[4];
      #pragma unroll
      for (int mi=0;mi<4;mi++){
        int row = wm*64 + mi*16 + (lane&15);
        int byte = (row*256 + kbyte) ^ ((row&7)<<4);
        af[mi] = *(const f16x8*)((const char*)a_lds + byte);
      }
      #pragma unroll
      for (int nj=0;nj<4;nj++){
        int nl = wn*64 + nj*16 + (lane&15);
        int byte = (nl*256 + kbyte) ^ ((nl&7)<<4);
        bf[nj] = *(const f16x8*)((const char*)b_lds + byte);
      }
      #pragma unroll
      for (int mi=0;mi<4;mi++)
        #pragma unroll
        for (int nj=0;nj<4;nj++)
          acc[mi][nj] = __builtin_amdgcn_mfma_f32_16x16x32_f16(af[mi], bf[nj], acc[mi][nj], 0, 0, 0);
    }
    __syncthreads();
  }
  // epilogue: C/D map: col = lane&15, row = (lane>>4)*4 + reg
  #pragma unroll
  for (int nj=0;nj<4;nj++){
    const int col = n0 + wn*64 + nj*16 + (lane & 15);
    const float bov = bo[col];
    #pragma unroll
    for (int mi=0;mi<4;mi++){
      const int rbase = m0 + wm*64 + mi*16 + (lane>>4)*4;
      #pragma unroll
      for (int r=0;r<4;r++){
        Y[(size_t)(rbase + r)*VV + col] = acc[mi][nj][r] + bov;
      }
    }
  }
}

extern "C" void kernel_launch(void* const* d_in, const int* in_sizes, int n_in,
                              void* d_out, int out_size, void* d_ws, size_t ws_size,
                              hipStream_t stream){
  const int*   X  = (const int*)d_in[0];
  const float* H0 = (const float*)d_in[1];
  const float* Wz = (const float*)d_in[2];
  const float* bz = (const float*)d_in[3];
  const float* Wr = (const float*)d_in[4];
  const float* br = (const float*)d_in[5];
  const float* Wh = (const float*)d_in[6];
  const float* bh = (const float*)d_in[7];
  const float* Wo = (const float*)d_in[8];
  const float* bo = (const float*)d_in[9];
  float* out = (float*)d_out;

  char* ws = (char*)d_ws;
  float*    g_buf = (float*)ws;                               // 4096*768*4  = 12,582,912 B
  uint32_t* Wpack = (uint32_t*)(ws + 12582912);               // 512*192*4   =    393,216 B
  f16*      Hn16  = (f16*)(ws + 12582912 + 393216);           // 4096*256*2  =  2,097,152 B

  k_gather<<<4096, 256, 0, stream>>>(X, Wz, bz, Wr, br, Wh, bh, g_buf);
  k_pack<<<384, 256, 0, stream>>>(Wz, Wr, Wh, Wpack);
  k_recur<<<32, 512, 0, stream>>>(H0, Wpack, g_buf, Hn16, out + 131072000LL);
  k_gemm<<<dim3(250, 32), 256, 0, stream>>>(Hn16, Wo, bo, out);
}

// Round 3
// 592.742 us; speedup vs baseline: 3.7414x; 1.2692x over previous
//
#include <hip/hip_runtime.h>
#include <hip/hip_fp16.h>
#include <stdint.h>

#define VV 32000
#define HH 256
#define BB 32
#define TT 128
#define VH 32256  // V + H

typedef _Float16 f16;
typedef _Float16 f16x2 __attribute__((ext_vector_type(2)));
typedef _Float16 f16x8 __attribute__((ext_vector_type(8)));
typedef float f32x4 __attribute__((ext_vector_type(4)));

// v_dot2_f32_f16: 2 f16 MACs with f32 accumulate in one instruction
static __device__ __forceinline__ float dot2f(uint32_t w, uint32_t h, float acc){
  f16x2 a = __builtin_bit_cast(f16x2, w);
  f16x2 b = __builtin_bit_cast(f16x2, h);
#if __has_builtin(__builtin_amdgcn_fdot2)
  return __builtin_amdgcn_fdot2(a, b, acc, false);
#else
  acc = fmaf((float)a[0], (float)b[0], acc);
  acc = fmaf((float)a[1], (float)b[1], acc);
  return acc;
#endif
}

// ---------------- gather: g[t*32+b][o] = W_gate[row][tok] + bias (o: 0..255 z, 256..511 r, 512..767 h)
__global__ void k_gather(const int* __restrict__ X,
                         const float* __restrict__ Wz, const float* __restrict__ bz,
                         const float* __restrict__ Wr, const float* __restrict__ br,
                         const float* __restrict__ Wh, const float* __restrict__ bh,
                         float* __restrict__ g_buf){
  int tb = blockIdx.x;              // t*32 + b
  int t = tb >> 5, b = tb & 31;
  int tok = X[b*TT + t];
  int o = threadIdx.x;              // 0..255
  g_buf[(size_t)tb*768 + o]       = Wz[(size_t)o*VH + tok] + bz[o];
  g_buf[(size_t)tb*768 + 256 + o] = Wr[(size_t)o*VH + tok] + br[o];
  g_buf[(size_t)tb*768 + 512 + o] = Wh[(size_t)o*VH + tok] + bh[o];
}

// ---------------- pack recurrent weights for 1024-thread k_recur layout
// thread t: ko = t&7 (K-chunk k in [ko*32, ko*32+32)), no = t>>3 in [0,128)
// ol<4  -> output o = no*4+ol  (o<256: Wz row o; else Wr row o-256)
// ol 4,5-> Wh row no*2+(ol-4)
// Wpack[t*96 + ol*16 + p] = f16x2{ W[row][VV + ko*32 + 2p], W[row][VV + ko*32 + 2p + 1] }
__global__ void k_pack(const float* __restrict__ Wz, const float* __restrict__ Wr,
                       const float* __restrict__ Wh, uint32_t* __restrict__ Wpack){
  int idx = blockIdx.x*256 + threadIdx.x;
  if (idx >= 1024*96) return;
  int t = idx / 96, rem = idx - t*96;
  int ol = rem >> 4, p = rem & 15;
  int ko = t & 7, no = t >> 3;
  int k = ko*32 + p*2;
  const float* W; int row;
  if (ol < 4){ int o = no*4 + ol; if (o < 256){ W = Wz; row = o; } else { W = Wr; row = o - 256; } }
  else { W = Wh; row = no*2 + (ol - 4); }
  float a = W[(size_t)row*VH + VV + k];
  float c = W[(size_t)row*VH + VV + k + 1];
  f16x2 v; v[0] = (f16)a; v[1] = (f16)c;
  Wpack[idx] = __builtin_bit_cast(uint32_t, v);
}

// ---------------- recurrence: 32 blocks (one batch chain each), 1024 threads, weights in regs/AGPRs
__global__ __launch_bounds__(1024) void k_recur(const float* __restrict__ H0,
                                                const uint32_t* __restrict__ Wpack,
                                                const float* __restrict__ g_buf,
                                                f16* __restrict__ Hn16,
                                                float* __restrict__ hf_out){
  __shared__ __align__(16) uint32_t hs16[128];   // Hs as f16 pairs (256 f16)
  __shared__ __align__(16) f16 rHs16[256];       // r*Hs as f16
  __shared__ float hs32[256];                    // Hs in f32 (state of record)
  __shared__ float z_s[256];

  const int b = blockIdx.x;
  const int tid = threadIdx.x;
  const int ko = tid & 7, no = tid >> 3;

  // 96 packed weight dwords per thread (static indices -> regs/AGPRs, no scratch)
  uint32_t w[6][16];
  {
    const uint4* src = (const uint4*)(Wpack + (size_t)tid*96);
    #pragma unroll
    for (int j=0;j<24;j++){
      uint4 v = src[j];
      int f = j*4;
      w[(f+0)>>4][(f+0)&15] = v.x;
      w[(f+1)>>4][(f+1)&15] = v.y;
      w[(f+2)>>4][(f+2)&15] = v.z;
      w[(f+3)>>4][(f+3)&15] = v.w;
    }
  }

  if (tid < 256) hs32[tid] = H0[b*HH + tid];
  __syncthreads();
  if (tid < 128){
    f16x2 v; v[0] = (f16)hs32[2*tid]; v[1] = (f16)hs32[2*tid+1];
    hs16[tid] = __builtin_bit_cast(uint32_t, v);
  }
  __syncthreads();

  // per-lane gate-input prefetch (replaces g_s LDS staging)
  const int gi1 = no*4 + ko;            // used when ko<4; ko>=4 reads in-row junk, ignored
  const int gi2 = 512 + no*2 + (ko & 1);
  float g1 = g_buf[(size_t)b*768 + gi1];
  float g2 = g_buf[(size_t)b*768 + gi2];
  float g1n = 0.f, g2n = 0.f;

  for (int t = 0; t < TT; t++){
    if (t < TT-1){
      const float* gn = g_buf + (size_t)((t+1)*BB + b)*768;
      g1n = gn[gi1];
      g2n = gn[gi2];
    }

    // ---- phase 1: z (groups no<64) and r (groups no>=64) pre-activations
    uint32_t hp[16];
    {
      const uint2* hsp = (const uint2*)hs16;
      #pragma unroll
      for (int j=0;j<8;j++){ uint2 v = hsp[ko*8 + j]; hp[2*j] = v.x; hp[2*j+1] = v.y; }
    }
    float acc[4];
    #pragma unroll
    for (int ol=0;ol<4;ol++) acc[ol] = 0.f;
    #pragma unroll
    for (int p=0;p<16;p++)
      #pragma unroll
      for (int ol=0;ol<4;ol++)
        acc[ol] = dot2f(w[ol][p], hp[p], acc[ol]);
    #pragma unroll
    for (int ol=0;ol<4;ol++){
      float v2 = acc[ol];
      v2 += __shfl_xor(v2, 1);
      v2 += __shfl_xor(v2, 2);
      v2 += __shfl_xor(v2, 4);
      acc[ol] = v2;
    }
    if (ko < 4){
      float pre = acc[ko] + g1;
      float s = 1.f / (1.f + __expf(-pre));
      int o = no*4 + ko;
      if (no < 64){
        z_s[o] = s;
      } else {
        int op = o - 256;
        rHs16[op] = (f16)(s * hs32[op]);
      }
    }
    __syncthreads();

    // ---- phase 2: h~ = tanh(gh + (r*Hs)@Wh^T), Hn = z*h~ + (1-z)*Hs
    uint32_t rp[16];
    {
      const uint2* rpp = (const uint2*)rHs16;
      #pragma unroll
      for (int j=0;j<8;j++){ uint2 v = rpp[ko*8 + j]; rp[2*j] = v.x; rp[2*j+1] = v.y; }
    }
    float a2[2];
    a2[0] = 0.f; a2[1] = 0.f;
    #pragma unroll
    for (int p=0;p<16;p++)
      #pragma unroll
      for (int oi=0;oi<2;oi++)
        a2[oi] = dot2f(w[4+oi][p], rp[p], a2[oi]);
    #pragma unroll
    for (int oi=0;oi<2;oi++){
      float v2 = a2[oi];
      v2 += __shfl_xor(v2, 1);
      v2 += __shfl_xor(v2, 2);
      v2 += __shfl_xor(v2, 4);
      a2[oi] = v2;
    }
    if (ko < 2){
      int o = no*2 + ko;
      float pre = a2[ko] + g2;
      float ax = fabsf(pre);
      float e = __expf(2.f*ax);
      float th = 1.f - 2.f/(e + 1.f);      // tanh(|x|), safe at inf
      th = copysignf(th, pre);
      float z = z_s[o];
      float hn = z*th + (1.f - z)*hs32[o];
      hs32[o] = hn;
      ((f16*)hs16)[o] = (f16)hn;
      Hn16[(size_t)(t*BB + b)*HH + o] = (f16)hn;
      if (t == TT-1) hf_out[b*HH + o] = hn;
    }
    g1 = g1n; g2 = g2n;
    __syncthreads();
  }
}

// ---------------- output GEMM: Y[4096][32000] = Hn16[4096][256] @ Wo^T (f16 MFMA) + bo
__global__ __launch_bounds__(256) void k_gemm(const f16* __restrict__ A, const float* __restrict__ Wo,
                                              const float* __restrict__ bo, float* __restrict__ Y){
  __shared__ __align__(16) f16 a_lds[128*128];
  __shared__ __align__(16) f16 b_lds[128*128];
  const int m0 = blockIdx.x * 128;   // m fastest -> consecutive blocks share Wo n-panel in L2
  const int n0 = blockIdx.y * 128;
  const int tid = threadIdx.x;
  const int lane = tid & 63, wave = tid >> 6;
  const int wm = wave >> 1, wn = wave & 1;

  f32x4 acc[4][4];
  {
    f32x4 z = {0.f, 0.f, 0.f, 0.f};
    #pragma unroll
    for (int i=0;i<4;i++)
      #pragma unroll
      for (int j=0;j<4;j++) acc[i][j] = z;
  }

  const int srow = tid >> 1, seg = tid & 1;
  #pragma unroll 1
  for (int kt=0; kt<2; kt++){
    const int k0 = kt*128;
    {
      const uint4* asrc = (const uint4*)(A + (size_t)(m0+srow)*256 + k0 + seg*64);
      #pragma unroll
      for (int j=0;j<8;j++){
        uint4 v = asrc[j];
        int byte = (srow*256 + seg*128 + j*16) ^ ((srow&7)<<4);
        *(uint4*)((char*)a_lds + byte) = v;
      }
      const float4* bsrc = (const float4*)(Wo + (size_t)(n0+srow)*256 + k0 + seg*64);
      #pragma unroll
      for (int j=0;j<8;j++){
        float4 f0 = bsrc[2*j], f1 = bsrc[2*j+1];
        f16x8 hv;
        hv[0]=(f16)f0.x; hv[1]=(f16)f0.y; hv[2]=(f16)f0.z; hv[3]=(f16)f0.w;
        hv[4]=(f16)f1.x; hv[5]=(f16)f1.y; hv[6]=(f16)f1.z; hv[7]=(f16)f1.w;
        int byte = (srow*256 + seg*128 + j*16) ^ ((srow&7)<<4);
        *(f16x8*)((char*)b_lds + byte) = hv;
      }
    }
    __syncthreads();
    #pragma unroll
    for (int kk=0; kk<4; kk++){
      const int kbyte = kk*64 + (lane>>4)*16;
      f16x8 af[4], bf[4];
      #pragma unroll
      for (int mi=0;mi<4;mi++){
        int row = wm*64 + mi*16 + (lane&15);
        int byte = (row*256 + kbyte) ^ ((row&7)<<4);
        af[mi] = *(const f16x8*)((const char*)a_lds + byte);
      }
      #pragma unroll
      for (int nj=0;nj<4;nj++){
        int nl = wn*64 + nj*16 + (lane&15);
        int byte = (nl*256 + kbyte) ^ ((nl&7)<<4);
        bf[nj] = *(const f16x8*)((const char*)b_lds + byte);
      }
      #pragma unroll
      for (int mi=0;mi<4;mi++)
        #pragma unroll
        for (int nj=0;nj<4;nj++)
          acc[mi][nj] = __builtin_amdgcn_mfma_f32_16x16x32_f16(af[mi], bf[nj], acc[mi][nj], 0, 0, 0);
    }
    __syncthreads();
  }
  // epilogue: C/D map: col = lane&15, row = (lane>>4)*4 + reg
  #pragma unroll
  for (int nj=0;nj<4;nj++){
    const int col = n0 + wn*64 + nj*16 + (lane & 15);
    const float bov = bo[col];
    #pragma unroll
    for (int mi=0;mi<4;mi++){
      const int rbase = m0 + wm*64 + mi*16 + (lane>>4)*4;
      #pragma unroll
      for (int r=0;r<4;r++){
        Y[(size_t)(rbase + r)*VV + col] = acc[mi][nj][r] + bov;
      }
    }
  }
}

extern "C" void kernel_launch(void* const* d_in, const int* in_sizes, int n_in,
                              void* d_out, int out_size, void* d_ws, size_t ws_size,
                              hipStream_t stream){
  const int*   X  = (const int*)d_in[0];
  const float* H0 = (const float*)d_in[1];
  const float* Wz = (const float*)d_in[2];
  const float* bz = (const float*)d_in[3];
  const float* Wr = (const float*)d_in[4];
  const float* br = (const float*)d_in[5];
  const float* Wh = (const float*)d_in[6];
  const float* bh = (const float*)d_in[7];
  const float* Wo = (const float*)d_in[8];
  const float* bo = (const float*)d_in[9];
  float* out = (float*)d_out;

  char* ws = (char*)d_ws;
  float*    g_buf = (float*)ws;                               // 4096*768*4  = 12,582,912 B
  uint32_t* Wpack = (uint32_t*)(ws + 12582912);               // 1024*96*4   =    393,216 B
  f16*      Hn16  = (f16*)(ws + 12582912 + 393216);           // 4096*256*2  =  2,097,152 B

  k_gather<<<4096, 256, 0, stream>>>(X, Wz, bz, Wr, br, Wh, bh, g_buf);
  k_pack<<<384, 256, 0, stream>>>(Wz, Wr, Wh, Wpack);
  k_recur<<<32, 1024, 0, stream>>>(H0, Wpack, g_buf, Hn16, out + 131072000LL);
  k_gemm<<<dim3(32, 250), 256, 0, stream>>>(Hn16, Wo, bo, out);
}